// Round 2
// baseline (14282.835 us; speedup 1.0000x reference)
//
#include <hip/hip_runtime.h>
#include <math.h>

#define BATCH 64
#define LPRE 256
#define EMBD 512
#define HID 1024
#define G3 3072
#define SRC 512
#define CHUNK 32

typedef unsigned int uint32;
typedef short bf16x8 __attribute__((ext_vector_type(8)));
typedef float f32x4 __attribute__((ext_vector_type(4)));

__device__ __forceinline__ float sigmoidf_(float x) { return 1.0f / (1.0f + __expf(-x)); }

__device__ __forceinline__ unsigned short f2bf(float f) {
    uint32 u = __float_as_uint(f);
    return (unsigned short)((u + 0x7fffu + ((u >> 16) & 1u)) >> 16);
}
__device__ __forceinline__ float bf2f(unsigned short s) { return __uint_as_float(((uint32)s) << 16); }
__device__ __forceinline__ void up2(uint32 u, float& f0, float& f1) {
    f0 = __uint_as_float(u << 16);
    f1 = __uint_as_float(u & 0xffff0000u);
}
__device__ __forceinline__ uint4 pack8(float4 a, float4 b) {
    uint4 w;
    w.x = (uint32)f2bf(a.x) | ((uint32)f2bf(a.y) << 16);
    w.y = (uint32)f2bf(a.z) | ((uint32)f2bf(a.w) << 16);
    w.z = (uint32)f2bf(b.x) | ((uint32)f2bf(b.y) << 16);
    w.w = (uint32)f2bf(b.z) | ((uint32)f2bf(b.w) << 16);
    return w;
}

// strided fp32 -> bf16 copy (weight pre-conversion)
__global__ __launch_bounds__(256) void kcvt(const float* __restrict__ src, int ld, int off,
                                            unsigned short* __restrict__ dst, int cols, int n) {
    int i = blockIdx.x * 256 + threadIdx.x;
    if (i >= n) return;
    int r = i / cols, c = i - r * cols;
    dst[i] = f2bf(src[(size_t)r * ld + off + c]);
}

// -------- MFMA projection: xw[row][col] = bih[col] + emb[tok(row)] . Wb[col]
// rows = (b, tloc) pairs for one 32-step chunk: row = b*CHUNK + tloc. 128x128 tiles.
__global__ __launch_bounds__(256) void kproj(const int* __restrict__ seq, int t0,
                                             const float* __restrict__ emb,
                                             const unsigned short* __restrict__ Wb,
                                             const float* __restrict__ bih,
                                             unsigned short* __restrict__ xwout) {
    __shared__ uint4 Asl[4][128];
    __shared__ uint4 Bsl[4][128];
    __shared__ int tok[128];
    int tid = threadIdx.x;
    int row0 = blockIdx.x * 128, col0 = blockIdx.y * 128;
    if (tid < 128) {
        int rr = row0 + tid;
        tok[tid] = seq[(rr >> 5) * LPRE + t0 + (rr & 31)];
    }
    __syncthreads();
    int lane = tid & 63, w = tid >> 6;
    int wm = w >> 1, wn = w & 1;
    int q = lane >> 4, m = lane & 15;
    int r0s = tid & 127, g0s = tid >> 7;            // slots tid and tid+256
    int r1s = r0s, g1s = g0s + 2;
    f32x4 acc[4][4] = {};
    for (int kk = 0; kk < EMBD; kk += 32) {
        const float* a0p = emb + (size_t)tok[r0s] * EMBD + kk + g0s * 8;
        const float* a1p = emb + (size_t)tok[r1s] * EMBD + kk + g1s * 8;
        float4 av00 = *(const float4*)a0p, av01 = *(const float4*)(a0p + 4);
        float4 av10 = *(const float4*)a1p, av11 = *(const float4*)(a1p + 4);
        uint4 bv0 = *(const uint4*)(Wb + (size_t)(col0 + r0s) * EMBD + kk + g0s * 8);
        uint4 bv1 = *(const uint4*)(Wb + (size_t)(col0 + r1s) * EMBD + kk + g1s * 8);
        __syncthreads();
        Asl[g0s][r0s] = pack8(av00, av01);
        Asl[g1s][r1s] = pack8(av10, av11);
        Bsl[g0s][r0s] = bv0;
        Bsl[g1s][r1s] = bv1;
        __syncthreads();
        bf16x8 af[4], bfv[4];
#pragma unroll
        for (int i = 0; i < 4; i++) af[i] = *(bf16x8*)&Asl[q][wm * 64 + i * 16 + m];
#pragma unroll
        for (int j = 0; j < 4; j++) bfv[j] = *(bf16x8*)&Bsl[q][wn * 64 + j * 16 + m];
#pragma unroll
        for (int i = 0; i < 4; i++)
#pragma unroll
            for (int j = 0; j < 4; j++)
                acc[i][j] = __builtin_amdgcn_mfma_f32_16x16x32_bf16(af[i], bfv[j], acc[i][j], 0, 0, 0);
    }
#pragma unroll
    for (int i = 0; i < 4; i++)
#pragma unroll
        for (int j = 0; j < 4; j++)
#pragma unroll
            for (int reg = 0; reg < 4; reg++) {
                int row = row0 + wm * 64 + i * 16 + q * 4 + reg;
                int col = col0 + wn * 64 + j * 16 + m;
                xwout[(size_t)row * G3 + col] = f2bf(acc[i][j][reg] + bih[col]);
            }
}

// -------- one GRU step (both GRUs via blockIdx.z). fp32 VALU; h staged bf16 in LDS.
__global__ __launch_bounds__(256) void kstep(const float* __restrict__ hin,
                                             float* __restrict__ hout,
                                             const float* __restrict__ Whh0,
                                             const float* __restrict__ bhh0,
                                             const float* __restrict__ Whh1,
                                             const float* __restrict__ bhh1,
                                             const unsigned short* __restrict__ xw,
                                             unsigned short* __restrict__ enc,
                                             int t, int tloc) {
    __shared__ unsigned short hs[32][1024];  // 64 KB
    int gru = blockIdx.z;
    int b0 = blockIdx.y * 32;
    int u0 = blockIdx.x * 8;
    int tid = threadIdx.x;
    const float* hbase = hin + (size_t)gru * BATCH * HID;
    for (int l = tid; l < 32 * 128; l += 256) {
        int r = l >> 7, j = l & 127;
        const float* hrow = hbase + (size_t)(b0 + r) * HID;
        float4 v0 = ((const float4*)hrow)[j * 2];
        float4 v1 = ((const float4*)hrow)[j * 2 + 1];
        uint4 wv;
        wv.x = (uint32)f2bf(v0.x) | ((uint32)f2bf(v0.y) << 16);
        wv.y = (uint32)f2bf(v0.z) | ((uint32)f2bf(v0.w) << 16);
        wv.z = (uint32)f2bf(v1.x) | ((uint32)f2bf(v1.y) << 16);
        wv.w = (uint32)f2bf(v1.z) | ((uint32)f2bf(v1.w) << 16);
        *((uint4*)&hs[r][(j ^ (r & 7)) << 3]) = wv;
    }
    __syncthreads();
    int bi = tid & 31, us = tid >> 5;
    const float* Whh = gru ? Whh1 : Whh0;
    const float* bhh = gru ? bhh1 : bhh0;
    int u = u0 + us;
    const float4* wr = (const float4*)(Whh + (size_t)u * HID);
    const float4* wz = (const float4*)(Whh + (size_t)(HID + u) * HID);
    const float4* wn = (const float4*)(Whh + (size_t)(2 * HID + u) * HID);
    float ar = 0.f, az = 0.f, an = 0.f;
    for (int j = 0; j < 128; ++j) {
        int js = j ^ (bi & 7);
        uint4 hv = *((const uint4*)&hs[bi][js << 3]);
        float h0, h1, h2, h3, h4, h5, h6, h7;
        up2(hv.x, h0, h1);
        up2(hv.y, h2, h3);
        up2(hv.z, h4, h5);
        up2(hv.w, h6, h7);
        float4 r0 = wr[js * 2], r1 = wr[js * 2 + 1];
        float4 z0 = wz[js * 2], z1 = wz[js * 2 + 1];
        float4 n0 = wn[js * 2], n1 = wn[js * 2 + 1];
        ar += h0 * r0.x + h1 * r0.y + h2 * r0.z + h3 * r0.w + h4 * r1.x + h5 * r1.y + h6 * r1.z + h7 * r1.w;
        az += h0 * z0.x + h1 * z0.y + h2 * z0.z + h3 * z0.w + h4 * z1.x + h5 * z1.y + h6 * z1.z + h7 * z1.w;
        an += h0 * n0.x + h1 * n0.y + h2 * n0.z + h3 * n0.w + h4 * n1.x + h5 * n1.y + h6 * n1.z + h7 * n1.w;
    }
    int b = b0 + bi;
    size_t xbase = ((size_t)(gru * BATCH + b) * CHUNK + tloc) * G3;
    float xr = bf2f(xw[xbase + u]);
    float xz = bf2f(xw[xbase + HID + u]);
    float xn = bf2f(xw[xbase + 2 * HID + u]);
    float r = sigmoidf_(xr + ar + bhh[u]);
    float z = sigmoidf_(xz + az + bhh[HID + u]);
    float n = tanhf(xn + r * (an + bhh[2 * HID + u]));
    int usw = ((u >> 3) ^ (bi & 7)) * 8 + (u & 7);
    float hold = bf2f(hs[bi][usw]);
    float hnew = (1.f - z) * n + z * hold;
    hout[((size_t)gru * BATCH + b) * HID + u] = hnew;
    enc[((size_t)b * SRC + gru * LPRE + t) * HID + u] = f2bf(hnew);
}

// -------- small fp32 GEMM: out[b][j] = act(A1[b].W[j][:K1] + A2[b].W[j][K1:] + bias)
__global__ __launch_bounds__(256) void ksmall(const float* __restrict__ A1, int K1,
                                              const float* __restrict__ A2, int K2,
                                              const float* __restrict__ W, int ldw,
                                              const float* __restrict__ bias,
                                              float* __restrict__ out, int N, int act) {
    int tid = threadIdx.x;
    int b = tid & 63;
    int jl = tid >> 6;
    int j = blockIdx.x * 4 + jl;
    const float* wrow = W + (size_t)j * ldw;
    float acc = 0.f;
    for (int k = 0; k < K1; k++) acc += A1[(size_t)b * K1 + k] * wrow[k];
    if (A2)
        for (int k = 0; k < K2; k++) acc += A2[(size_t)b * K2 + k] * wrow[K1 + k];
    if (bias) acc += bias[j];
    if (act == 1) acc = tanhf(acc);
    out[(size_t)b * N + j] = acc;
}

// -------- attention energies (MFMA): e[b,s] += sum_col vW[col]*tanh(enc.Wb + hidA + attn_b)
__global__ __launch_bounds__(256) void kattn(const unsigned short* __restrict__ enc,
                                             const unsigned short* __restrict__ Wb,
                                             const float* __restrict__ attn_b,
                                             const float* __restrict__ hidA,
                                             const float* __restrict__ vW,
                                             float* __restrict__ e) {
    __shared__ uint4 Asl[4][128];
    __shared__ uint4 Bsl[4][128];
    __shared__ float red[2][128][17];
    int tid = threadIdx.x;
    int row0 = blockIdx.x * 128, col0 = blockIdx.y * 128;
    int lane = tid & 63, w = tid >> 6;
    int wm = w >> 1, wn = w & 1;
    int q = lane >> 4, m = lane & 15;
    int r0s = tid & 127, g0s = tid >> 7;
    int g1s = g0s + 2;
    f32x4 acc[4][4] = {};
    for (int kk = 0; kk < HID; kk += 32) {
        uint4 av0 = *(const uint4*)(enc + (size_t)(row0 + r0s) * HID + kk + g0s * 8);
        uint4 av1 = *(const uint4*)(enc + (size_t)(row0 + r0s) * HID + kk + g1s * 8);
        uint4 bv0 = *(const uint4*)(Wb + (size_t)(col0 + r0s) * HID + kk + g0s * 8);
        uint4 bv1 = *(const uint4*)(Wb + (size_t)(col0 + r0s) * HID + kk + g1s * 8);
        __syncthreads();
        Asl[g0s][r0s] = av0;
        Asl[g1s][r0s] = av1;
        Bsl[g0s][r0s] = bv0;
        Bsl[g1s][r0s] = bv1;
        __syncthreads();
        bf16x8 af[4], bfv[4];
#pragma unroll
        for (int i = 0; i < 4; i++) af[i] = *(bf16x8*)&Asl[q][wm * 64 + i * 16 + m];
#pragma unroll
        for (int j = 0; j < 4; j++) bfv[j] = *(bf16x8*)&Bsl[q][wn * 64 + j * 16 + m];
#pragma unroll
        for (int i = 0; i < 4; i++)
#pragma unroll
            for (int j = 0; j < 4; j++)
                acc[i][j] = __builtin_amdgcn_mfma_f32_16x16x32_bf16(af[i], bfv[j], acc[i][j], 0, 0, 0);
    }
    int b = row0 / SRC;
#pragma unroll
    for (int i = 0; i < 4; i++)
#pragma unroll
        for (int reg = 0; reg < 4; reg++) {
            int row_local = wm * 64 + i * 16 + q * 4 + reg;
            float s = 0.f;
#pragma unroll
            for (int j = 0; j < 4; j++) {
                int col = col0 + wn * 64 + j * 16 + m;
                float v = acc[i][j][reg] + hidA[(size_t)b * HID + col] + attn_b[col];
                s += vW[col] * tanhf(v);
            }
            red[wn][row_local][m] = s;
        }
    __syncthreads();
    if (tid < 128) {
        float s = 0.f;
        for (int c = 0; c < 16; c++) s += red[0][tid][c] + red[1][tid][c];
        atomicAdd(e + row0 + tid, s);
    }
}

__global__ __launch_bounds__(256) void ksoftmax(const float* __restrict__ e, float* __restrict__ a) {
    int b = blockIdx.x;
    int tid = threadIdx.x;
    __shared__ float red[256];
    float v0 = e[(size_t)b * SRC + tid], v1 = e[(size_t)b * SRC + 256 + tid];
    red[tid] = fmaxf(v0, v1);
    __syncthreads();
    for (int st = 128; st > 0; st >>= 1) {
        if (tid < st) red[tid] = fmaxf(red[tid], red[tid + st]);
        __syncthreads();
    }
    float mx = red[0];
    __syncthreads();
    float e0 = __expf(v0 - mx), e1 = __expf(v1 - mx);
    red[tid] = e0 + e1;
    __syncthreads();
    for (int st = 128; st > 0; st >>= 1) {
        if (tid < st) red[tid] += red[tid + st];
        __syncthreads();
    }
    float inv = 1.0f / red[0];
    a[(size_t)b * SRC + tid] = e0 * inv;
    a[(size_t)b * SRC + 256 + tid] = e1 * inv;
}

__global__ __launch_bounds__(256) void kweighted(const float* __restrict__ a,
                                                 const unsigned short* __restrict__ enc,
                                                 float* __restrict__ wout) {
    int b = blockIdx.y;
    int h = blockIdx.x * 256 + threadIdx.x;
    __shared__ float as[512];
    for (int l = threadIdx.x; l < 512; l += 256) as[l] = a[(size_t)b * SRC + l];
    __syncthreads();
    float acc = 0.f;
    for (int s = 0; s < SRC; s++) acc += as[s] * bf2f(enc[((size_t)b * SRC + s) * HID + h]);
    wout[(size_t)b * HID + h] = acc;
}

__global__ __launch_bounds__(256) void koc(const float* __restrict__ o2,
                                           const float* __restrict__ fcoW,
                                           float* __restrict__ oc) {
    int b = blockIdx.x;
    int tid = threadIdx.x;
    __shared__ float red[256];
    float s = 0.f;
    for (int j = tid; j < HID; j += 256) s += fmaxf(o2[(size_t)b * HID + j], 0.f) * fcoW[HID + j];
    red[tid] = s;
    __syncthreads();
    for (int st = 128; st > 0; st >>= 1) {
        if (tid < st) red[tid] += red[tid + st];
        __syncthreads();
    }
    if (tid == 0) oc[b] = red[0];
}

__global__ __launch_bounds__(256) void kfinal(const unsigned short* __restrict__ enc,
                                              const float* __restrict__ fcoW,
                                              const float* __restrict__ fcob,
                                              const float* __restrict__ oc,
                                              float* __restrict__ out) {
    int s = blockIdx.x;
    int b = blockIdx.y;
    int tid = threadIdx.x;
    __shared__ float red[256];
    const unsigned short* er = enc + ((size_t)b * SRC + s) * HID;
    float acc = 0.f;
    for (int h = tid; h < HID; h += 256) acc += fmaxf(bf2f(er[h]), 0.f) * fcoW[h];
    red[tid] = acc;
    __syncthreads();
    for (int st = 128; st > 0; st >>= 1) {
        if (tid < st) red[tid] += red[tid + st];
        __syncthreads();
    }
    if (tid == 0) {
        float logit = red[0] + oc[b] + fcob[0];
        float sig = 1.f / (1.f + __expf(-logit));
        size_t base = (s < LPRE) ? ((size_t)b * 16 * 256 + s)
                                 : (262144 + (size_t)b * 16 * 256 + (s - 256));
        for (int l = 0; l < 16; l++) out[base + (size_t)l * 256] = sig;
    }
}

extern "C" void kernel_launch(void* const* d_in, const int* in_sizes, int n_in,
                              void* d_out, int out_size, void* d_ws, size_t ws_size,
                              hipStream_t stream) {
    (void)in_sizes; (void)n_in; (void)out_size; (void)ws_size;
    const int* pre_seq = (const int*)d_in[0];
    const int* post_seq = (const int*)d_in[1];
    const float* emb = (const float*)d_in[3];
    const float* Wih_pre = (const float*)d_in[4];
    const float* Whh_pre = (const float*)d_in[5];
    const float* bih_pre = (const float*)d_in[6];
    const float* bhh_pre = (const float*)d_in[7];
    const float* Wih_post = (const float*)d_in[8];
    const float* Whh_post = (const float*)d_in[9];
    const float* bih_post = (const float*)d_in[10];
    const float* bhh_post = (const float*)d_in[11];
    const float* fc_W = (const float*)d_in[12];
    const float* fc_b = (const float*)d_in[13];
    const float* attn_W = (const float*)d_in[14];
    const float* attn_b = (const float*)d_in[15];
    const float* v_W = (const float*)d_in[16];
    const float* fc1_W = (const float*)d_in[17];
    const float* fc1_b = (const float*)d_in[18];
    const float* fc2_W = (const float*)d_in[19];
    const float* fc2_b = (const float*)d_in[20];
    const float* fco_W = (const float*)d_in[21];
    const float* fco_b = (const float*)d_in[22];
    float* out = (float*)d_out;

    // workspace layout (~98.5 MB total; all 16B-aligned)
    char* ws = (char*)d_ws;
    unsigned short* xw = (unsigned short*)ws;   ws += (size_t)2 * BATCH * CHUNK * G3 * 2;   // 25.2 MB
    unsigned short* enc = (unsigned short*)ws;  ws += (size_t)BATCH * SRC * HID * 2;        // 67.1 MB
    float* hbuf = (float*)ws;                   ws += (size_t)2 * 2 * BATCH * HID * 4;      // 1.0 MB
    unsigned short* Wihb = (unsigned short*)ws; ws += (size_t)2 * G3 * EMBD * 2;            // 6.3 MB
    unsigned short* attnWb = (unsigned short*)ws; ws += (size_t)HID * HID * 2;              // 2.1 MB
    float* hidden = (float*)ws;                 ws += (size_t)BATCH * HID * 4;
    float* hidA = (float*)ws;                   ws += (size_t)BATCH * HID * 4;
    float* evec = (float*)ws;                   ws += (size_t)BATCH * SRC * 4;
    float* avec = (float*)ws;                   ws += (size_t)BATCH * SRC * 4;
    float* wsum = (float*)ws;                   ws += (size_t)BATCH * HID * 4;
    float* o1 = (float*)ws;                     ws += (size_t)BATCH * HID * 4;
    float* o2 = (float*)ws;                     ws += (size_t)BATCH * HID * 4;
    float* oc = (float*)ws;                     ws += (size_t)BATCH * 4;

    // per-call init (harness does not re-poison between replays)
    hipMemsetAsync(hbuf, 0, (size_t)2 * 2 * BATCH * HID * 4, stream);
    hipMemsetAsync(evec, 0, (size_t)BATCH * SRC * 4, stream);

    // weight pre-conversion to bf16
    {
        int n1 = G3 * EMBD;
        kcvt<<<(n1 + 255) / 256, 256, 0, stream>>>(Wih_pre, EMBD, 0, Wihb, EMBD, n1);
        kcvt<<<(n1 + 255) / 256, 256, 0, stream>>>(Wih_post, EMBD, 0, Wihb + (size_t)G3 * EMBD, EMBD, n1);
        int n2 = HID * HID;
        kcvt<<<(n2 + 255) / 256, 256, 0, stream>>>(attn_W, 2 * HID, HID, attnWb, HID, n2);
    }

    // chunked projection + sequential GRU steps
    for (int c = 0; c < LPRE / CHUNK; c++) {
        kproj<<<dim3(BATCH * CHUNK / 128, G3 / 128), 256, 0, stream>>>(
            pre_seq, c * CHUNK, emb, Wihb, bih_pre, xw);
        kproj<<<dim3(BATCH * CHUNK / 128, G3 / 128), 256, 0, stream>>>(
            post_seq, c * CHUNK, emb, Wihb + (size_t)G3 * EMBD, bih_post,
            xw + (size_t)BATCH * CHUNK * G3);
        for (int tl = 0; tl < CHUNK; tl++) {
            int t = c * CHUNK + tl;
            int p = t & 1;
            kstep<<<dim3(128, 2, 2), 256, 0, stream>>>(
                hbuf + (size_t)p * 2 * BATCH * HID,
                hbuf + (size_t)(p ^ 1) * 2 * BATCH * HID,
                Whh_pre, bhh_pre, Whh_post, bhh_post, xw, enc, t, tl);
        }
    }
    float* pre_h = hbuf;                         // after 256 steps, parity 0
    float* post_h = hbuf + (size_t)BATCH * HID;

    ksmall<<<HID / 4, 256, 0, stream>>>(pre_h, HID, post_h, HID, fc_W, 2 * HID, fc_b, hidden, HID, 1);
    ksmall<<<HID / 4, 256, 0, stream>>>(hidden, HID, (const float*)nullptr, 0, attn_W, 2 * HID,
                                        (const float*)nullptr, hidA, HID, 0);
    kattn<<<dim3(BATCH * SRC / 128, HID / 128), 256, 0, stream>>>(enc, attnWb, attn_b, hidA, v_W, evec);
    ksoftmax<<<BATCH, 256, 0, stream>>>(evec, avec);
    kweighted<<<dim3(HID / 256, BATCH), 256, 0, stream>>>(avec, enc, wsum);
    ksmall<<<HID / 4, 256, 0, stream>>>(hidden, HID, (const float*)nullptr, 0, fc1_W, HID, fc1_b, o1, HID, 1);
    ksmall<<<HID / 4, 256, 0, stream>>>(o1, HID, wsum, HID, fc2_W, 2 * HID, fc2_b, o2, HID, 1);
    koc<<<BATCH, 256, 0, stream>>>(o2, fco_W, oc);
    kfinal<<<dim3(SRC, BATCH), 256, 0, stream>>>(enc, fco_W, fco_b, oc, out);
}

// Round 3
// 9521.476 us; speedup vs baseline: 1.5001x; 1.5001x over previous
//
#include <hip/hip_runtime.h>
#include <math.h>

#define BATCH 64
#define LPRE 256
#define EMBD 512
#define HID 1024
#define G3 3072
#define SRC 512
#define CHUNK 32

typedef unsigned int uint32;
typedef short bf16x8 __attribute__((ext_vector_type(8)));
typedef float f32x4 __attribute__((ext_vector_type(4)));

__device__ __forceinline__ float frcp_(float x) { return __builtin_amdgcn_rcpf(x); }
__device__ __forceinline__ float sigmoidf_(float x) {
    x = fminf(fmaxf(x, -30.f), 30.f);
    return frcp_(1.0f + __expf(-x));
}
__device__ __forceinline__ float tanhf_(float x) {
    x = fminf(fmaxf(x, -15.f), 15.f);
    float e = __expf(2.f * x);
    return (e - 1.f) * frcp_(e + 1.f);
}

__device__ __forceinline__ unsigned short f2bf(float f) {
    uint32 u = __float_as_uint(f);
    return (unsigned short)((u + 0x7fffu + ((u >> 16) & 1u)) >> 16);
}
__device__ __forceinline__ float bf2f(unsigned short s) { return __uint_as_float(((uint32)s) << 16); }
__device__ __forceinline__ uint4 pack8(float4 a, float4 b) {
    uint4 w;
    w.x = (uint32)f2bf(a.x) | ((uint32)f2bf(a.y) << 16);
    w.y = (uint32)f2bf(a.z) | ((uint32)f2bf(a.w) << 16);
    w.z = (uint32)f2bf(b.x) | ((uint32)f2bf(b.y) << 16);
    w.w = (uint32)f2bf(b.z) | ((uint32)f2bf(b.w) << 16);
    return w;
}

// strided fp32 -> bf16 copy (weight pre-conversion)
__global__ __launch_bounds__(256) void kcvt(const float* __restrict__ src, int ld, int off,
                                            unsigned short* __restrict__ dst, int cols, int n) {
    int i = blockIdx.x * 256 + threadIdx.x;
    if (i >= n) return;
    int r = i / cols, c = i - r * cols;
    dst[i] = f2bf(src[(size_t)r * ld + off + c]);
}

// -------- MFMA projection, both GRUs via blockIdx.z. 128x128 tiles.
__global__ __launch_bounds__(256) void kproj(const int* __restrict__ pre_seq,
                                             const int* __restrict__ post_seq, int t0,
                                             const float* __restrict__ emb,
                                             const unsigned short* __restrict__ Wihb,
                                             const float* __restrict__ bih_pre,
                                             const float* __restrict__ bih_post,
                                             unsigned short* __restrict__ xw) {
    __shared__ uint4 Asl[4][128];
    __shared__ uint4 Bsl[4][128];
    __shared__ int tok[128];
    int gru = blockIdx.z;
    const int* seq = gru ? post_seq : pre_seq;
    const unsigned short* Wb = Wihb + (size_t)gru * G3 * EMBD;
    const float* bih = gru ? bih_post : bih_pre;
    unsigned short* xwout = xw + (size_t)gru * BATCH * CHUNK * G3;
    int tid = threadIdx.x;
    int row0 = blockIdx.x * 128, col0 = blockIdx.y * 128;
    if (tid < 128) {
        int rr = row0 + tid;
        tok[tid] = seq[(rr >> 5) * LPRE + t0 + (rr & 31)];
    }
    __syncthreads();
    int lane = tid & 63, w = tid >> 6;
    int wm = w >> 1, wn = w & 1;
    int q = lane >> 4, m = lane & 15;
    int r0s = tid & 127, g0s = tid >> 7;
    int g1s = g0s + 2;
    f32x4 acc[4][4] = {};
    for (int kk = 0; kk < EMBD; kk += 32) {
        const float* a0p = emb + (size_t)tok[r0s] * EMBD + kk + g0s * 8;
        const float* a1p = emb + (size_t)tok[r0s] * EMBD + kk + g1s * 8;
        float4 av00 = *(const float4*)a0p, av01 = *(const float4*)(a0p + 4);
        float4 av10 = *(const float4*)a1p, av11 = *(const float4*)(a1p + 4);
        uint4 bv0 = *(const uint4*)(Wb + (size_t)(col0 + r0s) * EMBD + kk + g0s * 8);
        uint4 bv1 = *(const uint4*)(Wb + (size_t)(col0 + r0s) * EMBD + kk + g1s * 8);
        __syncthreads();
        Asl[g0s][r0s ^ (g0s << 2)] = pack8(av00, av01);
        Asl[g1s][r0s ^ (g1s << 2)] = pack8(av10, av11);
        Bsl[g0s][r0s ^ (g0s << 2)] = bv0;
        Bsl[g1s][r0s ^ (g1s << 2)] = bv1;
        __syncthreads();
        bf16x8 af[4], bfv[4];
#pragma unroll
        for (int i = 0; i < 4; i++) af[i] = *(bf16x8*)&Asl[q][(wm * 64 + i * 16 + m) ^ (q << 2)];
#pragma unroll
        for (int j = 0; j < 4; j++) bfv[j] = *(bf16x8*)&Bsl[q][(wn * 64 + j * 16 + m) ^ (q << 2)];
#pragma unroll
        for (int i = 0; i < 4; i++)
#pragma unroll
            for (int j = 0; j < 4; j++)
                acc[i][j] = __builtin_amdgcn_mfma_f32_16x16x32_bf16(af[i], bfv[j], acc[i][j], 0, 0, 0);
    }
#pragma unroll
    for (int i = 0; i < 4; i++)
#pragma unroll
        for (int j = 0; j < 4; j++)
#pragma unroll
            for (int reg = 0; reg < 4; reg++) {
                int row = row0 + wm * 64 + i * 16 + q * 4 + reg;
                int col = col0 + wn * 64 + j * 16 + m;
                xwout[(size_t)row * G3 + col] = f2bf(acc[i][j][reg] + bih[col]);
            }
}

// -------- fused MFMA GRU step. Block = 2 waves, tile: 64 batch x 32 units x 3 gates.
__global__ __launch_bounds__(128) void kstep2(const unsigned short* __restrict__ hbin,
                                              unsigned short* __restrict__ hbout,
                                              float* __restrict__ hf,
                                              const unsigned short* __restrict__ Whhb,
                                              const float* __restrict__ bhh0,
                                              const float* __restrict__ bhh1,
                                              const unsigned short* __restrict__ xw,
                                              unsigned short* __restrict__ enc,
                                              int t, int tloc) {
    __shared__ uint4 Asl[4][64];      // 4 KB : h tile   [q][batch]
    __shared__ uint4 Bsl[3][4][32];   // 6 KB : weights  [gate][q][unit]
    int gru = blockIdx.y;
    int u0 = blockIdx.x * 32;
    int tid = threadIdx.x;
    int lane = tid & 63, w = tid >> 6;       // w in {0,1}: unit sub-tile
    int q = lane >> 4, m = lane & 15;
    const unsigned short* hb = hbin + (size_t)gru * BATCH * HID;
    const unsigned short* Wg = Whhb + (size_t)gru * G3 * HID;
    int arow = tid >> 2, aq = tid & 3;       // A slot 0 (slot 1 = +128 threads)
    int arow1 = (tid + 128) >> 2;
    int ul = tid >> 2;                       // B row (0..31)
    f32x4 acc[4][3] = {};
    for (int kk = 0; kk < HID; kk += 32) {
        uint4 av0 = *(const uint4*)(hb + (size_t)arow * HID + kk + aq * 8);
        uint4 av1 = *(const uint4*)(hb + (size_t)arow1 * HID + kk + aq * 8);
        uint4 bv[3];
#pragma unroll
        for (int gt = 0; gt < 3; gt++)
            bv[gt] = *(const uint4*)(Wg + (size_t)(gt * HID + u0 + ul) * HID + kk + aq * 8);
        __syncthreads();
        Asl[aq][arow ^ (aq << 2)] = av0;
        Asl[aq][arow1 ^ (aq << 2)] = av1;
#pragma unroll
        for (int gt = 0; gt < 3; gt++) Bsl[gt][aq][ul ^ (aq << 2)] = bv[gt];
        __syncthreads();
        bf16x8 af[4], bfv[3];
#pragma unroll
        for (int i = 0; i < 4; i++) af[i] = *(bf16x8*)&Asl[q][(i * 16 + m) ^ (q << 2)];
#pragma unroll
        for (int gt = 0; gt < 3; gt++) bfv[gt] = *(bf16x8*)&Bsl[gt][q][(w * 16 + m) ^ (q << 2)];
#pragma unroll
        for (int i = 0; i < 4; i++)
#pragma unroll
            for (int gt = 0; gt < 3; gt++)
                acc[i][gt] = __builtin_amdgcn_mfma_f32_16x16x32_bf16(af[i], bfv[gt], acc[i][gt], 0, 0, 0);
    }
    int u = u0 + w * 16 + m;
    const float* bhh = gru ? bhh1 : bhh0;
    float br = bhh[u], bz = bhh[HID + u], bn = bhh[2 * HID + u];
#pragma unroll
    for (int i = 0; i < 4; i++)
#pragma unroll
        for (int reg = 0; reg < 4; reg++) {
            int b = i * 16 + q * 4 + reg;
            size_t xbase = ((size_t)(gru * BATCH + b) * CHUNK + tloc) * G3;
            float xr = bf2f(xw[xbase + u]);
            float xz = bf2f(xw[xbase + HID + u]);
            float xn = bf2f(xw[xbase + 2 * HID + u]);
            float r = sigmoidf_(xr + acc[i][0][reg] + br);
            float z = sigmoidf_(xz + acc[i][1][reg] + bz);
            float n = tanhf_(xn + r * (acc[i][2][reg] + bn));
            float hold = bf2f(hb[(size_t)b * HID + u]);
            float hnew = (1.f - z) * n + z * hold;
            unsigned short h16 = f2bf(hnew);
            hbout[((size_t)gru * BATCH + b) * HID + u] = h16;
            hf[((size_t)gru * BATCH + b) * HID + u] = hnew;
            enc[((size_t)b * SRC + gru * LPRE + t) * HID + u] = h16;
        }
}

// -------- small fp32 GEMM: out[b][j] = act(A1[b].W[j][:K1] + A2[b].W[j][K1:] + bias)
__global__ __launch_bounds__(256) void ksmall(const float* __restrict__ A1, int K1,
                                              const float* __restrict__ A2, int K2,
                                              const float* __restrict__ W, int ldw,
                                              const float* __restrict__ bias,
                                              float* __restrict__ out, int N, int act) {
    int tid = threadIdx.x;
    int b = tid & 63;
    int jl = tid >> 6;
    int j = blockIdx.x * 4 + jl;
    const float* wrow = W + (size_t)j * ldw;
    float acc = 0.f;
    for (int k = 0; k < K1; k++) acc += A1[(size_t)b * K1 + k] * wrow[k];
    if (A2)
        for (int k = 0; k < K2; k++) acc += A2[(size_t)b * K2 + k] * wrow[K1 + k];
    if (bias) acc += bias[j];
    if (act == 1) acc = tanhf(acc);
    out[(size_t)b * N + j] = acc;
}

// -------- attention energies (MFMA)
__global__ __launch_bounds__(256) void kattn(const unsigned short* __restrict__ enc,
                                             const unsigned short* __restrict__ Wb,
                                             const float* __restrict__ attn_b,
                                             const float* __restrict__ hidA,
                                             const float* __restrict__ vW,
                                             float* __restrict__ e) {
    __shared__ uint4 Asl[4][128];
    __shared__ uint4 Bsl[4][128];
    __shared__ float red[2][128][17];
    int tid = threadIdx.x;
    int row0 = blockIdx.x * 128, col0 = blockIdx.y * 128;
    int lane = tid & 63, w = tid >> 6;
    int wm = w >> 1, wn = w & 1;
    int q = lane >> 4, m = lane & 15;
    int r0s = tid & 127, g0s = tid >> 7;
    int g1s = g0s + 2;
    f32x4 acc[4][4] = {};
    for (int kk = 0; kk < HID; kk += 32) {
        uint4 av0 = *(const uint4*)(enc + (size_t)(row0 + r0s) * HID + kk + g0s * 8);
        uint4 av1 = *(const uint4*)(enc + (size_t)(row0 + r0s) * HID + kk + g1s * 8);
        uint4 bv0 = *(const uint4*)(Wb + (size_t)(col0 + r0s) * HID + kk + g0s * 8);
        uint4 bv1 = *(const uint4*)(Wb + (size_t)(col0 + r0s) * HID + kk + g1s * 8);
        __syncthreads();
        Asl[g0s][r0s ^ (g0s << 2)] = av0;
        Asl[g1s][r0s ^ (g1s << 2)] = av1;
        Bsl[g0s][r0s ^ (g0s << 2)] = bv0;
        Bsl[g1s][r0s ^ (g1s << 2)] = bv1;
        __syncthreads();
        bf16x8 af[4], bfv[4];
#pragma unroll
        for (int i = 0; i < 4; i++) af[i] = *(bf16x8*)&Asl[q][(wm * 64 + i * 16 + m) ^ (q << 2)];
#pragma unroll
        for (int j = 0; j < 4; j++) bfv[j] = *(bf16x8*)&Bsl[q][(wn * 64 + j * 16 + m) ^ (q << 2)];
#pragma unroll
        for (int i = 0; i < 4; i++)
#pragma unroll
            for (int j = 0; j < 4; j++)
                acc[i][j] = __builtin_amdgcn_mfma_f32_16x16x32_bf16(af[i], bfv[j], acc[i][j], 0, 0, 0);
    }
    int b = row0 / SRC;
#pragma unroll
    for (int i = 0; i < 4; i++)
#pragma unroll
        for (int reg = 0; reg < 4; reg++) {
            int row_local = wm * 64 + i * 16 + q * 4 + reg;
            float s = 0.f;
#pragma unroll
            for (int j = 0; j < 4; j++) {
                int col = col0 + wn * 64 + j * 16 + m;
                float v = acc[i][j][reg] + hidA[(size_t)b * HID + col] + attn_b[col];
                s += vW[col] * tanhf(v);
            }
            red[wn][row_local][m] = s;
        }
    __syncthreads();
    if (tid < 128) {
        float s = 0.f;
        for (int c = 0; c < 16; c++) s += red[0][tid][c] + red[1][tid][c];
        atomicAdd(e + row0 + tid, s);
    }
}

__global__ __launch_bounds__(256) void ksoftmax(const float* __restrict__ e, float* __restrict__ a) {
    int b = blockIdx.x;
    int tid = threadIdx.x;
    __shared__ float red[256];
    float v0 = e[(size_t)b * SRC + tid], v1 = e[(size_t)b * SRC + 256 + tid];
    red[tid] = fmaxf(v0, v1);
    __syncthreads();
    for (int st = 128; st > 0; st >>= 1) {
        if (tid < st) red[tid] = fmaxf(red[tid], red[tid + st]);
        __syncthreads();
    }
    float mx = red[0];
    __syncthreads();
    float e0 = __expf(v0 - mx), e1 = __expf(v1 - mx);
    red[tid] = e0 + e1;
    __syncthreads();
    for (int st = 128; st > 0; st >>= 1) {
        if (tid < st) red[tid] += red[tid + st];
        __syncthreads();
    }
    float inv = 1.0f / red[0];
    a[(size_t)b * SRC + tid] = e0 * inv;
    a[(size_t)b * SRC + 256 + tid] = e1 * inv;
}

__global__ __launch_bounds__(256) void kweighted(const float* __restrict__ a,
                                                 const unsigned short* __restrict__ enc,
                                                 float* __restrict__ wout) {
    int b = blockIdx.y;
    int h = blockIdx.x * 256 + threadIdx.x;
    __shared__ float as[512];
    for (int l = threadIdx.x; l < 512; l += 256) as[l] = a[(size_t)b * SRC + l];
    __syncthreads();
    float acc = 0.f;
    for (int s = 0; s < SRC; s++) acc += as[s] * bf2f(enc[((size_t)b * SRC + s) * HID + h]);
    wout[(size_t)b * HID + h] = acc;
}

__global__ __launch_bounds__(256) void koc(const float* __restrict__ o2,
                                           const float* __restrict__ fcoW,
                                           float* __restrict__ oc) {
    int b = blockIdx.x;
    int tid = threadIdx.x;
    __shared__ float red[256];
    float s = 0.f;
    for (int j = tid; j < HID; j += 256) s += fmaxf(o2[(size_t)b * HID + j], 0.f) * fcoW[HID + j];
    red[tid] = s;
    __syncthreads();
    for (int st = 128; st > 0; st >>= 1) {
        if (tid < st) red[tid] += red[tid + st];
        __syncthreads();
    }
    if (tid == 0) oc[b] = red[0];
}

__global__ __launch_bounds__(256) void kfinal(const unsigned short* __restrict__ enc,
                                              const float* __restrict__ fcoW,
                                              const float* __restrict__ fcob,
                                              const float* __restrict__ oc,
                                              float* __restrict__ out) {
    int s = blockIdx.x;
    int b = blockIdx.y;
    int tid = threadIdx.x;
    __shared__ float red[256];
    const unsigned short* er = enc + ((size_t)b * SRC + s) * HID;
    float acc = 0.f;
    for (int h = tid; h < HID; h += 256) acc += fmaxf(bf2f(er[h]), 0.f) * fcoW[h];
    red[tid] = acc;
    __syncthreads();
    for (int st = 128; st > 0; st >>= 1) {
        if (tid < st) red[tid] += red[tid + st];
        __syncthreads();
    }
    if (tid == 0) {
        float logit = red[0] + oc[b] + fcob[0];
        float sig = 1.f / (1.f + __expf(-logit));
        size_t base = (s < LPRE) ? ((size_t)b * 16 * 256 + s)
                                 : (262144 + (size_t)b * 16 * 256 + (s - 256));
        for (int l = 0; l < 16; l++) out[base + (size_t)l * 256] = sig;
    }
}

extern "C" void kernel_launch(void* const* d_in, const int* in_sizes, int n_in,
                              void* d_out, int out_size, void* d_ws, size_t ws_size,
                              hipStream_t stream) {
    (void)in_sizes; (void)n_in; (void)out_size; (void)ws_size;
    const int* pre_seq = (const int*)d_in[0];
    const int* post_seq = (const int*)d_in[1];
    const float* emb = (const float*)d_in[3];
    const float* Wih_pre = (const float*)d_in[4];
    const float* Whh_pre = (const float*)d_in[5];
    const float* bih_pre = (const float*)d_in[6];
    const float* bhh_pre = (const float*)d_in[7];
    const float* Wih_post = (const float*)d_in[8];
    const float* Whh_post = (const float*)d_in[9];
    const float* bih_post = (const float*)d_in[10];
    const float* bhh_post = (const float*)d_in[11];
    const float* fc_W = (const float*)d_in[12];
    const float* fc_b = (const float*)d_in[13];
    const float* attn_W = (const float*)d_in[14];
    const float* attn_b = (const float*)d_in[15];
    const float* v_W = (const float*)d_in[16];
    const float* fc1_W = (const float*)d_in[17];
    const float* fc1_b = (const float*)d_in[18];
    const float* fc2_W = (const float*)d_in[19];
    const float* fc2_b = (const float*)d_in[20];
    const float* fco_W = (const float*)d_in[21];
    const float* fco_b = (const float*)d_in[22];
    float* out = (float*)d_out;

    // workspace layout (~115 MB total; all 16B-aligned)
    char* ws = (char*)d_ws;
    unsigned short* xw = (unsigned short*)ws;     ws += (size_t)2 * BATCH * CHUNK * G3 * 2;  // 25.2 MB
    unsigned short* enc = (unsigned short*)ws;    ws += (size_t)BATCH * SRC * HID * 2;       // 67.1 MB
    unsigned short* hbp = (unsigned short*)ws;    ws += (size_t)2 * 2 * BATCH * HID * 2;     // 0.5 MB (parity x gru)
    float* hf = (float*)ws;                       ws += (size_t)2 * BATCH * HID * 4;         // 0.5 MB
    unsigned short* Wihb = (unsigned short*)ws;   ws += (size_t)2 * G3 * EMBD * 2;           // 6.3 MB
    unsigned short* Whhb = (unsigned short*)ws;   ws += (size_t)2 * G3 * HID * 2;            // 12.6 MB
    unsigned short* attnWb = (unsigned short*)ws; ws += (size_t)HID * HID * 2;               // 2.1 MB
    float* hidden = (float*)ws;                   ws += (size_t)BATCH * HID * 4;
    float* hidA = (float*)ws;                     ws += (size_t)BATCH * HID * 4;
    float* evec = (float*)ws;                     ws += (size_t)BATCH * SRC * 4;
    float* avec = (float*)ws;                     ws += (size_t)BATCH * SRC * 4;
    float* wsum = (float*)ws;                     ws += (size_t)BATCH * HID * 4;
    float* o1 = (float*)ws;                       ws += (size_t)BATCH * HID * 4;
    float* o2 = (float*)ws;                       ws += (size_t)BATCH * HID * 4;
    float* oc = (float*)ws;                       ws += (size_t)BATCH * 4;

    // per-call init (harness does not re-poison between replays)
    hipMemsetAsync(hbp, 0, (size_t)2 * 2 * BATCH * HID * 2, stream);
    hipMemsetAsync(evec, 0, (size_t)BATCH * SRC * 4, stream);

    // weight pre-conversion to bf16
    {
        int n1 = G3 * EMBD;
        kcvt<<<(n1 + 255) / 256, 256, 0, stream>>>(Wih_pre, EMBD, 0, Wihb, EMBD, n1);
        kcvt<<<(n1 + 255) / 256, 256, 0, stream>>>(Wih_post, EMBD, 0, Wihb + (size_t)G3 * EMBD, EMBD, n1);
        int n2 = G3 * HID;
        kcvt<<<(n2 + 255) / 256, 256, 0, stream>>>(Whh_pre, HID, 0, Whhb, HID, n2);
        kcvt<<<(n2 + 255) / 256, 256, 0, stream>>>(Whh_post, HID, 0, Whhb + (size_t)G3 * HID, HID, n2);
        int n3 = HID * HID;
        kcvt<<<(n3 + 255) / 256, 256, 0, stream>>>(attn_W, 2 * HID, HID, attnWb, HID, n3);
    }

    // chunked projection + sequential fused-MFMA GRU steps
    for (int c = 0; c < LPRE / CHUNK; c++) {
        kproj<<<dim3(BATCH * CHUNK / 128, G3 / 128, 2), 256, 0, stream>>>(
            pre_seq, post_seq, c * CHUNK, emb, Wihb, bih_pre, bih_post, xw);
        for (int tl = 0; tl < CHUNK; tl++) {
            int t = c * CHUNK + tl;
            int p = t & 1;
            kstep2<<<dim3(32, 2), 128, 0, stream>>>(
                hbp + (size_t)p * 2 * BATCH * HID,
                hbp + (size_t)(p ^ 1) * 2 * BATCH * HID,
                hf, Whhb, bhh_pre, bhh_post, xw, enc, t, tl);
        }
    }
    float* pre_h = hf;                       // f32 copy of final h
    float* post_h = hf + (size_t)BATCH * HID;

    ksmall<<<HID / 4, 256, 0, stream>>>(pre_h, HID, post_h, HID, fc_W, 2 * HID, fc_b, hidden, HID, 1);
    ksmall<<<HID / 4, 256, 0, stream>>>(hidden, HID, (const float*)nullptr, 0, attn_W, 2 * HID,
                                        (const float*)nullptr, hidA, HID, 0);
    kattn<<<dim3(BATCH * SRC / 128, HID / 128), 256, 0, stream>>>(enc, attnWb, attn_b, hidA, v_W, evec);
    ksoftmax<<<BATCH, 256, 0, stream>>>(evec, avec);
    kweighted<<<dim3(HID / 256, BATCH), 256, 0, stream>>>(avec, enc, wsum);
    ksmall<<<HID / 4, 256, 0, stream>>>(hidden, HID, (const float*)nullptr, 0, fc1_W, HID, fc1_b, o1, HID, 1);
    ksmall<<<HID / 4, 256, 0, stream>>>(o1, HID, wsum, HID, fc2_W, 2 * HID, fc2_b, o2, HID, 1);
    koc<<<BATCH, 256, 0, stream>>>(o2, fco_W, oc);
    kfinal<<<dim3(SRC, BATCH), 256, 0, stream>>>(enc, fco_W, fco_b, oc, out);
}

// Round 4
// 4245.662 us; speedup vs baseline: 3.3641x; 2.2426x over previous
//
#include <hip/hip_runtime.h>
#include <math.h>

#define BATCH 64
#define LPRE 256
#define EMBD 512
#define HID 1024
#define G3 3072
#define SRC 512
#define CHUNK 32

typedef unsigned int uint32;
typedef short bf16x8 __attribute__((ext_vector_type(8)));
typedef float f32x4 __attribute__((ext_vector_type(4)));

__device__ __forceinline__ float frcp_(float x) { return __builtin_amdgcn_rcpf(x); }
__device__ __forceinline__ float sigmoidf_(float x) {
    x = fminf(fmaxf(x, -30.f), 30.f);
    return frcp_(1.0f + __expf(-x));
}
__device__ __forceinline__ float tanhf_(float x) {
    x = fminf(fmaxf(x, -15.f), 15.f);
    float e = __expf(2.f * x);
    return (e - 1.f) * frcp_(e + 1.f);
}

__device__ __forceinline__ unsigned short f2bf(float f) {
    uint32 u = __float_as_uint(f);
    return (unsigned short)((u + 0x7fffu + ((u >> 16) & 1u)) >> 16);
}
__device__ __forceinline__ float bf2f(unsigned short s) { return __uint_as_float(((uint32)s) << 16); }
__device__ __forceinline__ uint4 pack8(float4 a, float4 b) {
    uint4 w;
    w.x = (uint32)f2bf(a.x) | ((uint32)f2bf(a.y) << 16);
    w.y = (uint32)f2bf(a.z) | ((uint32)f2bf(a.w) << 16);
    w.z = (uint32)f2bf(b.x) | ((uint32)f2bf(b.y) << 16);
    w.w = (uint32)f2bf(b.z) | ((uint32)f2bf(b.w) << 16);
    return w;
}

// strided fp32 -> bf16 copy (weight pre-conversion)
__global__ __launch_bounds__(256) void kcvt(const float* __restrict__ src, int ld, int off,
                                            unsigned short* __restrict__ dst, int cols, int n) {
    int i = blockIdx.x * 256 + threadIdx.x;
    if (i >= n) return;
    int r = i / cols, c = i - r * cols;
    dst[i] = f2bf(src[(size_t)r * ld + off + c]);
}

// -------- MFMA projection, both GRUs via blockIdx.z. 128x128 tiles.
__global__ __launch_bounds__(256) void kproj(const int* __restrict__ pre_seq,
                                             const int* __restrict__ post_seq, int t0,
                                             const float* __restrict__ emb,
                                             const unsigned short* __restrict__ Wihb,
                                             const float* __restrict__ bih_pre,
                                             const float* __restrict__ bih_post,
                                             unsigned short* __restrict__ xw) {
    __shared__ uint4 Asl[4][128];
    __shared__ uint4 Bsl[4][128];
    __shared__ int tok[128];
    int gru = blockIdx.z;
    const int* seq = gru ? post_seq : pre_seq;
    const unsigned short* Wb = Wihb + (size_t)gru * G3 * EMBD;
    const float* bih = gru ? bih_post : bih_pre;
    unsigned short* xwout = xw + (size_t)gru * BATCH * CHUNK * G3;
    int tid = threadIdx.x;
    int row0 = blockIdx.x * 128, col0 = blockIdx.y * 128;
    if (tid < 128) {
        int rr = row0 + tid;
        tok[tid] = seq[(rr >> 5) * LPRE + t0 + (rr & 31)];
    }
    __syncthreads();
    int lane = tid & 63, w = tid >> 6;
    int wm = w >> 1, wn = w & 1;
    int q = lane >> 4, m = lane & 15;
    int r0s = tid & 127, g0s = tid >> 7;
    int g1s = g0s + 2;
    f32x4 acc[4][4] = {};
    for (int kk = 0; kk < EMBD; kk += 32) {
        const float* a0p = emb + (size_t)tok[r0s] * EMBD + kk + g0s * 8;
        const float* a1p = emb + (size_t)tok[r0s] * EMBD + kk + g1s * 8;
        float4 av00 = *(const float4*)a0p, av01 = *(const float4*)(a0p + 4);
        float4 av10 = *(const float4*)a1p, av11 = *(const float4*)(a1p + 4);
        uint4 bv0 = *(const uint4*)(Wb + (size_t)(col0 + r0s) * EMBD + kk + g0s * 8);
        uint4 bv1 = *(const uint4*)(Wb + (size_t)(col0 + r0s) * EMBD + kk + g1s * 8);
        __syncthreads();
        Asl[g0s][r0s ^ (g0s << 2)] = pack8(av00, av01);
        Asl[g1s][r0s ^ (g1s << 2)] = pack8(av10, av11);
        Bsl[g0s][r0s ^ (g0s << 2)] = bv0;
        Bsl[g1s][r0s ^ (g1s << 2)] = bv1;
        __syncthreads();
        bf16x8 af[4], bfv[4];
#pragma unroll
        for (int i = 0; i < 4; i++) af[i] = *(bf16x8*)&Asl[q][(wm * 64 + i * 16 + m) ^ (q << 2)];
#pragma unroll
        for (int j = 0; j < 4; j++) bfv[j] = *(bf16x8*)&Bsl[q][(wn * 64 + j * 16 + m) ^ (q << 2)];
#pragma unroll
        for (int i = 0; i < 4; i++)
#pragma unroll
            for (int j = 0; j < 4; j++)
                acc[i][j] = __builtin_amdgcn_mfma_f32_16x16x32_bf16(af[i], bfv[j], acc[i][j], 0, 0, 0);
    }
#pragma unroll
    for (int i = 0; i < 4; i++)
#pragma unroll
        for (int j = 0; j < 4; j++)
#pragma unroll
            for (int reg = 0; reg < 4; reg++) {
                int row = row0 + wm * 64 + i * 16 + q * 4 + reg;
                int col = col0 + wn * 64 + j * 16 + m;
                xwout[(size_t)row * G3 + col] = f2bf(acc[i][j][reg] + bih[col]);
            }
}

// -------- fused MFMA GRU step, v3.
// 256 blocks x 384 thr. Block = (gru, batch-half 32, 16-unit tile).
// Wave = (gate, K-half): B streamed global->reg (exclusive), A (h) global->frag (L1-shared).
// Gates combined via small LDS; gate math + h update fused in epilogue.
__global__ __launch_bounds__(384) void kstep3(const unsigned short* __restrict__ hbin,
                                              unsigned short* __restrict__ hbout,
                                              float* __restrict__ hf,
                                              const unsigned short* __restrict__ Whhb,
                                              const float* __restrict__ bhh0,
                                              const float* __restrict__ bhh1,
                                              const unsigned short* __restrict__ xw,
                                              unsigned short* __restrict__ enc,
                                              int t, int tloc) {
    __shared__ float gl[2][32][3][17];   // [khalf][batch32][gate][unit16+pad] = 13 KB
    int gru = blockIdx.z;
    int mh = blockIdx.y;                  // batches mh*32 .. +31
    int u0 = blockIdx.x * 16;
    int tid = threadIdx.x;
    int w = tid >> 6;                     // 0..5
    int lane = tid & 63;
    int q = lane >> 4, m = lane & 15;
    int g = (w < 3) ? w : w - 3;
    int kh = (w < 3) ? 0 : 1;
    const unsigned short* hb = hbin + (size_t)gru * BATCH * HID;
    const unsigned short* Wg = Whhb + (size_t)gru * G3 * HID;
    int bbase = mh * 32;
    const unsigned short* pa0 = hb + (size_t)(bbase + m) * HID + kh * 512 + q * 8;
    const unsigned short* pa1 = pa0 + (size_t)16 * HID;
    const unsigned short* pb = Wg + (size_t)(g * HID + u0 + m) * HID + kh * 512 + q * 8;
    f32x4 acc0 = {}, acc1 = {};
#pragma unroll 4
    for (int it = 0; it < 16; ++it) {
        bf16x8 af0 = *(const bf16x8*)(pa0 + it * 32);
        bf16x8 af1 = *(const bf16x8*)(pa1 + it * 32);
        bf16x8 bfv = *(const bf16x8*)(pb + it * 32);
        acc0 = __builtin_amdgcn_mfma_f32_16x16x32_bf16(af0, bfv, acc0, 0, 0, 0);
        acc1 = __builtin_amdgcn_mfma_f32_16x16x32_bf16(af1, bfv, acc1, 0, 0, 0);
    }
#pragma unroll
    for (int reg = 0; reg < 4; ++reg) {
        gl[kh][q * 4 + reg][g][m] = acc0[reg];
        gl[kh][16 + q * 4 + reg][g][m] = acc1[reg];
    }
    __syncthreads();
    const float* bhh = gru ? bhh1 : bhh0;
    for (int l = tid; l < 512; l += 384) {
        int bl = l >> 4, ul = l & 15;
        int b = bbase + bl, u = u0 + ul;
        float ar = gl[0][bl][0][ul] + gl[1][bl][0][ul];
        float az = gl[0][bl][1][ul] + gl[1][bl][1][ul];
        float an = gl[0][bl][2][ul] + gl[1][bl][2][ul];
        size_t xbase = ((size_t)(gru * BATCH + b) * CHUNK + tloc) * G3;
        float xr = bf2f(xw[xbase + u]);
        float xz = bf2f(xw[xbase + HID + u]);
        float xn = bf2f(xw[xbase + 2 * HID + u]);
        float r = sigmoidf_(xr + ar + bhh[u]);
        float z = sigmoidf_(xz + az + bhh[HID + u]);
        float n = tanhf_(xn + r * (an + bhh[2 * HID + u]));
        float hold = bf2f(hb[(size_t)b * HID + u]);
        float hnew = (1.f - z) * n + z * hold;
        unsigned short h16 = f2bf(hnew);
        hbout[((size_t)gru * BATCH + b) * HID + u] = h16;
        enc[((size_t)b * SRC + gru * LPRE + t) * HID + u] = h16;
        if (t == LPRE - 1) hf[((size_t)gru * BATCH + b) * HID + u] = hnew;
    }
}

// -------- small fp32 GEMM: out[b][j] = act(A1[b].W[j][:K1] + A2[b].W[j][K1:] + bias)
__global__ __launch_bounds__(256) void ksmall(const float* __restrict__ A1, int K1,
                                              const float* __restrict__ A2, int K2,
                                              const float* __restrict__ W, int ldw,
                                              const float* __restrict__ bias,
                                              float* __restrict__ out, int N, int act) {
    int tid = threadIdx.x;
    int b = tid & 63;
    int jl = tid >> 6;
    int j = blockIdx.x * 4 + jl;
    const float* wrow = W + (size_t)j * ldw;
    float acc = 0.f;
    for (int k = 0; k < K1; k++) acc += A1[(size_t)b * K1 + k] * wrow[k];
    if (A2)
        for (int k = 0; k < K2; k++) acc += A2[(size_t)b * K2 + k] * wrow[K1 + k];
    if (bias) acc += bias[j];
    if (act == 1) acc = tanhf(acc);
    out[(size_t)b * N + j] = acc;
}

// -------- attention energies (MFMA)
__global__ __launch_bounds__(256) void kattn(const unsigned short* __restrict__ enc,
                                             const unsigned short* __restrict__ Wb,
                                             const float* __restrict__ attn_b,
                                             const float* __restrict__ hidA,
                                             const float* __restrict__ vW,
                                             float* __restrict__ e) {
    __shared__ uint4 Asl[4][128];
    __shared__ uint4 Bsl[4][128];
    __shared__ float red[2][128][17];
    int tid = threadIdx.x;
    int row0 = blockIdx.x * 128, col0 = blockIdx.y * 128;
    int lane = tid & 63, w = tid >> 6;
    int wm = w >> 1, wn = w & 1;
    int q = lane >> 4, m = lane & 15;
    int r0s = tid & 127, g0s = tid >> 7;
    int g1s = g0s + 2;
    f32x4 acc[4][4] = {};
    for (int kk = 0; kk < HID; kk += 32) {
        uint4 av0 = *(const uint4*)(enc + (size_t)(row0 + r0s) * HID + kk + g0s * 8);
        uint4 av1 = *(const uint4*)(enc + (size_t)(row0 + r0s) * HID + kk + g1s * 8);
        uint4 bv0 = *(const uint4*)(Wb + (size_t)(col0 + r0s) * HID + kk + g0s * 8);
        uint4 bv1 = *(const uint4*)(Wb + (size_t)(col0 + r0s) * HID + kk + g1s * 8);
        __syncthreads();
        Asl[g0s][r0s ^ (g0s << 2)] = av0;
        Asl[g1s][r0s ^ (g1s << 2)] = av1;
        Bsl[g0s][r0s ^ (g0s << 2)] = bv0;
        Bsl[g1s][r0s ^ (g1s << 2)] = bv1;
        __syncthreads();
        bf16x8 af[4], bfv[4];
#pragma unroll
        for (int i = 0; i < 4; i++) af[i] = *(bf16x8*)&Asl[q][(wm * 64 + i * 16 + m) ^ (q << 2)];
#pragma unroll
        for (int j = 0; j < 4; j++) bfv[j] = *(bf16x8*)&Bsl[q][(wn * 64 + j * 16 + m) ^ (q << 2)];
#pragma unroll
        for (int i = 0; i < 4; i++)
#pragma unroll
            for (int j = 0; j < 4; j++)
                acc[i][j] = __builtin_amdgcn_mfma_f32_16x16x32_bf16(af[i], bfv[j], acc[i][j], 0, 0, 0);
    }
    int b = row0 / SRC;
#pragma unroll
    for (int i = 0; i < 4; i++)
#pragma unroll
        for (int reg = 0; reg < 4; reg++) {
            int row_local = wm * 64 + i * 16 + q * 4 + reg;
            float s = 0.f;
#pragma unroll
            for (int j = 0; j < 4; j++) {
                int col = col0 + wn * 64 + j * 16 + m;
                float v = acc[i][j][reg] + hidA[(size_t)b * HID + col] + attn_b[col];
                s += vW[col] * tanhf(v);
            }
            red[wn][row_local][m] = s;
        }
    __syncthreads();
    if (tid < 128) {
        float s = 0.f;
        for (int c = 0; c < 16; c++) s += red[0][tid][c] + red[1][tid][c];
        atomicAdd(e + row0 + tid, s);
    }
}

__global__ __launch_bounds__(256) void ksoftmax(const float* __restrict__ e, float* __restrict__ a) {
    int b = blockIdx.x;
    int tid = threadIdx.x;
    __shared__ float red[256];
    float v0 = e[(size_t)b * SRC + tid], v1 = e[(size_t)b * SRC + 256 + tid];
    red[tid] = fmaxf(v0, v1);
    __syncthreads();
    for (int st = 128; st > 0; st >>= 1) {
        if (tid < st) red[tid] = fmaxf(red[tid], red[tid + st]);
        __syncthreads();
    }
    float mx = red[0];
    __syncthreads();
    float e0 = __expf(v0 - mx), e1 = __expf(v1 - mx);
    red[tid] = e0 + e1;
    __syncthreads();
    for (int st = 128; st > 0; st >>= 1) {
        if (tid < st) red[tid] += red[tid + st];
        __syncthreads();
    }
    float inv = 1.0f / red[0];
    a[(size_t)b * SRC + tid] = e0 * inv;
    a[(size_t)b * SRC + 256 + tid] = e1 * inv;
}

__global__ __launch_bounds__(256) void kweighted(const float* __restrict__ a,
                                                 const unsigned short* __restrict__ enc,
                                                 float* __restrict__ wout) {
    int b = blockIdx.y;
    int h = blockIdx.x * 256 + threadIdx.x;
    __shared__ float as[512];
    for (int l = threadIdx.x; l < 512; l += 256) as[l] = a[(size_t)b * SRC + l];
    __syncthreads();
    float acc = 0.f;
    for (int s = 0; s < SRC; s++) acc += as[s] * bf2f(enc[((size_t)b * SRC + s) * HID + h]);
    wout[(size_t)b * HID + h] = acc;
}

__global__ __launch_bounds__(256) void koc(const float* __restrict__ o2,
                                           const float* __restrict__ fcoW,
                                           float* __restrict__ oc) {
    int b = blockIdx.x;
    int tid = threadIdx.x;
    __shared__ float red[256];
    float s = 0.f;
    for (int j = tid; j < HID; j += 256) s += fmaxf(o2[(size_t)b * HID + j], 0.f) * fcoW[HID + j];
    red[tid] = s;
    __syncthreads();
    for (int st = 128; st > 0; st >>= 1) {
        if (tid < st) red[tid] += red[tid + st];
        __syncthreads();
    }
    if (tid == 0) oc[b] = red[0];
}

__global__ __launch_bounds__(256) void kfinal(const unsigned short* __restrict__ enc,
                                              const float* __restrict__ fcoW,
                                              const float* __restrict__ fcob,
                                              const float* __restrict__ oc,
                                              float* __restrict__ out) {
    int s = blockIdx.x;
    int b = blockIdx.y;
    int tid = threadIdx.x;
    __shared__ float red[256];
    const unsigned short* er = enc + ((size_t)b * SRC + s) * HID;
    float acc = 0.f;
    for (int h = tid; h < HID; h += 256) acc += fmaxf(bf2f(er[h]), 0.f) * fcoW[h];
    red[tid] = acc;
    __syncthreads();
    for (int st = 128; st > 0; st >>= 1) {
        if (tid < st) red[tid] += red[tid + st];
        __syncthreads();
    }
    if (tid == 0) {
        float logit = red[0] + oc[b] + fcob[0];
        float sig = 1.f / (1.f + __expf(-logit));
        size_t base = (s < LPRE) ? ((size_t)b * 16 * 256 + s)
                                 : (262144 + (size_t)b * 16 * 256 + (s - 256));
        for (int l = 0; l < 16; l++) out[base + (size_t)l * 256] = sig;
    }
}

extern "C" void kernel_launch(void* const* d_in, const int* in_sizes, int n_in,
                              void* d_out, int out_size, void* d_ws, size_t ws_size,
                              hipStream_t stream) {
    (void)in_sizes; (void)n_in; (void)out_size; (void)ws_size;
    const int* pre_seq = (const int*)d_in[0];
    const int* post_seq = (const int*)d_in[1];
    const float* emb = (const float*)d_in[3];
    const float* Wih_pre = (const float*)d_in[4];
    const float* Whh_pre = (const float*)d_in[5];
    const float* bih_pre = (const float*)d_in[6];
    const float* bhh_pre = (const float*)d_in[7];
    const float* Wih_post = (const float*)d_in[8];
    const float* Whh_post = (const float*)d_in[9];
    const float* bih_post = (const float*)d_in[10];
    const float* bhh_post = (const float*)d_in[11];
    const float* fc_W = (const float*)d_in[12];
    const float* fc_b = (const float*)d_in[13];
    const float* attn_W = (const float*)d_in[14];
    const float* attn_b = (const float*)d_in[15];
    const float* v_W = (const float*)d_in[16];
    const float* fc1_W = (const float*)d_in[17];
    const float* fc1_b = (const float*)d_in[18];
    const float* fc2_W = (const float*)d_in[19];
    const float* fc2_b = (const float*)d_in[20];
    const float* fco_W = (const float*)d_in[21];
    const float* fco_b = (const float*)d_in[22];
    float* out = (float*)d_out;

    // workspace layout (~115 MB total; all 16B-aligned)
    char* ws = (char*)d_ws;
    unsigned short* xw = (unsigned short*)ws;     ws += (size_t)2 * BATCH * CHUNK * G3 * 2;  // 25.2 MB
    unsigned short* enc = (unsigned short*)ws;    ws += (size_t)BATCH * SRC * HID * 2;       // 67.1 MB
    unsigned short* hbp = (unsigned short*)ws;    ws += (size_t)2 * 2 * BATCH * HID * 2;     // 0.5 MB (parity x gru)
    float* hf = (float*)ws;                       ws += (size_t)2 * BATCH * HID * 4;         // 0.5 MB
    unsigned short* Wihb = (unsigned short*)ws;   ws += (size_t)2 * G3 * EMBD * 2;           // 6.3 MB
    unsigned short* Whhb = (unsigned short*)ws;   ws += (size_t)2 * G3 * HID * 2;            // 12.6 MB
    unsigned short* attnWb = (unsigned short*)ws; ws += (size_t)HID * HID * 2;               // 2.1 MB
    float* hidden = (float*)ws;                   ws += (size_t)BATCH * HID * 4;
    float* hidA = (float*)ws;                     ws += (size_t)BATCH * HID * 4;
    float* evec = (float*)ws;                     ws += (size_t)BATCH * SRC * 4;
    float* avec = (float*)ws;                     ws += (size_t)BATCH * SRC * 4;
    float* wsum = (float*)ws;                     ws += (size_t)BATCH * HID * 4;
    float* o1 = (float*)ws;                       ws += (size_t)BATCH * HID * 4;
    float* o2 = (float*)ws;                       ws += (size_t)BATCH * HID * 4;
    float* oc = (float*)ws;                       ws += (size_t)BATCH * 4;

    // per-call init (harness does not re-poison between replays)
    hipMemsetAsync(hbp, 0, (size_t)2 * 2 * BATCH * HID * 2, stream);
    hipMemsetAsync(evec, 0, (size_t)BATCH * SRC * 4, stream);

    // weight pre-conversion to bf16
    {
        int n1 = G3 * EMBD;
        kcvt<<<(n1 + 255) / 256, 256, 0, stream>>>(Wih_pre, EMBD, 0, Wihb, EMBD, n1);
        kcvt<<<(n1 + 255) / 256, 256, 0, stream>>>(Wih_post, EMBD, 0, Wihb + (size_t)G3 * EMBD, EMBD, n1);
        int n2 = G3 * HID;
        kcvt<<<(n2 + 255) / 256, 256, 0, stream>>>(Whh_pre, HID, 0, Whhb, HID, n2);
        kcvt<<<(n2 + 255) / 256, 256, 0, stream>>>(Whh_post, HID, 0, Whhb + (size_t)G3 * HID, HID, n2);
        int n3 = HID * HID;
        kcvt<<<(n3 + 255) / 256, 256, 0, stream>>>(attn_W, 2 * HID, HID, attnWb, HID, n3);
    }

    // chunked projection + sequential fused-MFMA GRU steps
    for (int c = 0; c < LPRE / CHUNK; c++) {
        kproj<<<dim3(BATCH * CHUNK / 128, G3 / 128, 2), 256, 0, stream>>>(
            pre_seq, post_seq, c * CHUNK, emb, Wihb, bih_pre, bih_post, xw);
        for (int tl = 0; tl < CHUNK; tl++) {
            int t = c * CHUNK + tl;
            int p = t & 1;
            kstep3<<<dim3(64, 2, 2), 384, 0, stream>>>(
                hbp + (size_t)p * 2 * BATCH * HID,
                hbp + (size_t)(p ^ 1) * 2 * BATCH * HID,
                hf, Whhb, bhh_pre, bhh_post, xw, enc, t, tl);
        }
    }
    float* pre_h = hf;                       // f32 copy of final h
    float* post_h = hf + (size_t)BATCH * HID;

    ksmall<<<HID / 4, 256, 0, stream>>>(pre_h, HID, post_h, HID, fc_W, 2 * HID, fc_b, hidden, HID, 1);
    ksmall<<<HID / 4, 256, 0, stream>>>(hidden, HID, (const float*)nullptr, 0, attn_W, 2 * HID,
                                        (const float*)nullptr, hidA, HID, 0);
    kattn<<<dim3(BATCH * SRC / 128, HID / 128), 256, 0, stream>>>(enc, attnWb, attn_b, hidA, v_W, evec);
    ksoftmax<<<BATCH, 256, 0, stream>>>(evec, avec);
    kweighted<<<dim3(HID / 256, BATCH), 256, 0, stream>>>(avec, enc, wsum);
    ksmall<<<HID / 4, 256, 0, stream>>>(hidden, HID, (const float*)nullptr, 0, fc1_W, HID, fc1_b, o1, HID, 1);
    ksmall<<<HID / 4, 256, 0, stream>>>(o1, HID, wsum, HID, fc2_W, 2 * HID, fc2_b, o2, HID, 1);
    koc<<<BATCH, 256, 0, stream>>>(o2, fco_W, oc);
    kfinal<<<dim3(SRC, BATCH), 256, 0, stream>>>(enc, fco_W, fco_b, oc, out);
}